// Round 6
// baseline (154.564 us; speedup 1.0000x reference)
//
#include <hip/hip_runtime.h>
#include <stdint.h>

typedef int i32x4  __attribute__((ext_vector_type(4)));
typedef int i32x16 __attribute__((ext_vector_type(16)));

static constexpr int Mdim   = 16384;     // B*S = 8*2048
static constexpr int Kdim   = 2048;      // D_IN
static constexpr int Ndim   = 2048;      // D_OUT
static constexpr int WELEMS = Ndim * Kdim;   // 4194304

// Fragment-major pack layout (shared by packers and GEMM):
//   chunk(R, c) = 1024 B at base + (R*64 + c)*1024
//   byte l*16 + b of a chunk holds row R*32 + (l&31), k = c*32 + (l>>5)*16 + b
// so the GEMM's global_load_lds (dest = base + lane*16) reads contiguous 1 KiB.

// ---------------- async global->LDS (16B per lane, lane-ordered dest) -------
__device__ __forceinline__ void gload_lds16(const void* g, void* l) {
  __builtin_amdgcn_global_load_lds(
      (const __attribute__((address_space(1))) void*)g,
      (__attribute__((address_space(3))) void*)l,
      16, 0, 0);
}

// ---------------- K1: partial sums of |w| -----------------------------------
__global__ void k_abs_part(const float* __restrict__ w, float* __restrict__ part) {
  const float4* w4 = (const float4*)w;
  float s = 0.f;
  int idx = blockIdx.x * 256 + threadIdx.x;
  #pragma unroll 4
  for (int i = idx; i < WELEMS / 4; i += 256 * 256) {
    float4 v = w4[i];
    s += fabsf(v.x) + fabsf(v.y) + fabsf(v.z) + fabsf(v.w);
  }
  #pragma unroll
  for (int off = 32; off > 0; off >>= 1) s += __shfl_down(s, off);
  __shared__ float sm[4];
  if ((threadIdx.x & 63) == 0) sm[threadIdx.x >> 6] = s;
  __syncthreads();
  if (threadIdx.x == 0) part[blockIdx.x] = sm[0] + sm[1] + sm[2] + sm[3];
}

// ---------------- K2: finalize scale = mean(|w|) ----------------------------
__global__ void k_abs_final(const float* __restrict__ part, float* __restrict__ scal) {
  float s = part[threadIdx.x];           // exactly 256 partials, block = 256
  #pragma unroll
  for (int off = 32; off > 0; off >>= 1) s += __shfl_down(s, off);
  __shared__ float sm[4];
  if ((threadIdx.x & 63) == 0) sm[threadIdx.x >> 6] = s;
  __syncthreads();
  if (threadIdx.x == 0) scal[0] = (sm[0] + sm[1] + sm[2] + sm[3]) / (float)WELEMS;
}

__device__ __forceinline__ int quant4(float4 v, float sc) {
  int a = (int)rintf(v.x / sc); a = a < -128 ? -128 : (a > 127 ? 127 : a);
  int b = (int)rintf(v.y / sc); b = b < -128 ? -128 : (b > 127 ? 127 : b);
  int c = (int)rintf(v.z / sc); c = c < -128 ? -128 : (c > 127 ? 127 : c);
  int d = (int)rintf(v.w / sc); d = d < -128 ? -128 : (d > 127 ? 127 : d);
  return (a & 255) | ((b & 255) << 8) | ((c & 255) << 16) | ((d & 255) << 24);
}

__device__ __forceinline__ int tern4(float4 v, float s) {
  int a = (int)rintf(v.x / s); a = a < -1 ? -1 : (a > 1 ? 1 : a);
  int b = (int)rintf(v.y / s); b = b < -1 ? -1 : (b > 1 ? 1 : b);
  int c = (int)rintf(v.z / s); c = c < -1 ? -1 : (c > 1 ? 1 : c);
  int d = (int)rintf(v.w / s); d = d < -1 ? -1 : (d > 1 ? 1 : d);
  return (a & 255) | ((b & 255) << 8) | ((c & 255) << 16) | ((d & 255) << 24);
}

// LDS row stride for the transpose buffers: 2052 B (513 dwords, odd ->
// bank = (l*513 + k)%32 spreads 32 rows over all 32 banks; <=2-way = free).
static constexpr int LSTR = 2052;

// ---------------- K3: ternary weight quantize + fragment-major pack ---------
// grid 64 blocks x 256 thr; block = 32 rows of w.
__global__ __launch_bounds__(256) void k_wquant(const float* __restrict__ w,
                                                char* __restrict__ wq,
                                                const float* __restrict__ scal) {
  __shared__ char sq[32 * LSTR];
  const float s  = scal[0] + 1e-8f;
  const int   Rg = blockIdx.x;
  const int   wv = threadIdx.x >> 6;
  const int   l  = threadIdx.x & 63;

  #pragma unroll 2
  for (int it = 0; it < 8; ++it) {
    const int rs = it * 4 + wv;          // row slot 0..31
    const float4* wr = (const float4*)(w + (size_t)(Rg * 32 + rs) * Kdim);
    #pragma unroll
    for (int c = 0; c < 8; ++c)
      *(int*)(&sq[rs * LSTR + (c * 64 + l) * 4]) = tern4(wr[c * 64 + l], s);
  }
  __syncthreads();
  char* dst = wq + (size_t)Rg * 65536;
  #pragma unroll 4
  for (int i = 0; i < 16; ++i) {
    const int c = i * 4 + wv;            // chunk 0..63
    int p[4];
    #pragma unroll
    for (int j = 0; j < 4; ++j)
      p[j] = *(const int*)(&sq[(l & 31) * LSTR + c * 32 + (l >> 5) * 16 + j * 4]);
    *(int4*)(dst + c * 1024 + l * 16) = make_int4(p[0], p[1], p[2], p[3]);
  }
}

// ---------------- K4: per-row absmax + int8 quantize + pack -----------------
// grid 512 blocks x 256 thr; block = 32 rows of x. One row per wave-iter ->
// absmax is a pure shfl reduce; fp32 reads and pack writes fully coalesced.
__global__ __launch_bounds__(256) void k_xquant(const float* __restrict__ x,
                                                char* __restrict__ xq,
                                                float* __restrict__ xs) {
  __shared__ char sq[32 * LSTR];
  const int Rg = blockIdx.x;
  const int wv = threadIdx.x >> 6;
  const int l  = threadIdx.x & 63;

  #pragma unroll 2
  for (int it = 0; it < 8; ++it) {
    const int rs  = it * 4 + wv;
    const int row = Rg * 32 + rs;
    const float4* xr = (const float4*)(x + (size_t)row * Kdim);
    float4 v[8];
    float  m = 0.f;
    #pragma unroll
    for (int c = 0; c < 8; ++c) {
      v[c] = xr[c * 64 + l];
      m = fmaxf(m, fmaxf(fmaxf(fabsf(v[c].x), fabsf(v[c].y)),
                         fmaxf(fabsf(v[c].z), fabsf(v[c].w))));
    }
    #pragma unroll
    for (int off = 1; off < 64; off <<= 1) m = fmaxf(m, __shfl_xor(m, off));
    m = fmaxf(m, 1e-8f);
    const float sc = m / 127.0f;
    if (l == 0) xs[row] = sc;
    #pragma unroll
    for (int c = 0; c < 8; ++c)
      *(int*)(&sq[rs * LSTR + (c * 64 + l) * 4]) = quant4(v[c], sc);
  }
  __syncthreads();
  char* dst = xq + (size_t)Rg * 65536;
  #pragma unroll 4
  for (int i = 0; i < 16; ++i) {
    const int c = i * 4 + wv;
    int p[4];
    #pragma unroll
    for (int j = 0; j < 4; ++j)
      p[j] = *(const int*)(&sq[(l & 31) * LSTR + c * 32 + (l >> 5) * 16 + j * 4]);
    *(int4*)(dst + c * 1024 + l * 16) = make_int4(p[0], p[1], p[2], p[3]);
  }
}

// ---------------- K5: int8 MFMA GEMM, 256x256 tile, BK=64, 4-buf ring -------
// out = (scale*xs[m]) * (xq . wq^T) + bias
// 8 waves (2M x 4N), wave tile 128x64 = acc[4][2] of 32x32 mfma.
// Counted-vmcnt pipeline: prefetch 3 K-tiles ahead, s_waitcnt vmcnt(8) +
// raw s_barrier once per K-tile; vmcnt never drains to 0 in the main loop.
// Staging sources are fragment-major packed -> each gload_lds reads a
// CONTIGUOUS 1024 B (8 full cache lines) and K-tiles stream sequentially.
__global__ __launch_bounds__(512, 2) void k_gemm(
    const char* __restrict__ xq, const char* __restrict__ wq,
    const float* __restrict__ xs, const float* __restrict__ scal,
    const float* __restrict__ bias, float* __restrict__ out) {
  __shared__ __attribute__((aligned(128))) char lds[4][32768];

  // XCD-aware bijective swizzle: 512 blocks, 512 % 8 == 0.
  const int hw  = blockIdx.x;
  const int lin = (hw & 7) * 64 + (hw >> 3);
  const int bm  = lin >> 3;               // 64 M-tiles
  const int bn  = lin & 7;                // 8 N-tiles

  const int tid = threadIdx.x;
  const int w   = tid >> 6;               // wave 0..7
  const int l   = tid & 63;
  const int wr  = w >> 2, wc = w & 3;     // 2 x 4 wave grid
  const int l16 = l * 16;

  // packed sources: wave w stages R-group (bm*8 + w) of A, (bn*8 + w) of B
  const char* gA = xq + (size_t)(bm * 8 + w) * 65536 + l16;
  const char* gB = wq + (size_t)(bn * 8 + w) * 65536 + l16;
  const int   w2k = w * 2048;

#define STAGE(t_)                                                         \
  {                                                                       \
    char* sb = &lds[(t_) & 3][0];                                         \
    const int kb_ = (t_) * 2048;                                          \
    gload_lds16(gA + kb_,        sb + w2k);                               \
    gload_lds16(gA + kb_ + 1024, sb + w2k + 1024);                        \
    gload_lds16(gB + kb_,        sb + 16384 + w2k);                       \
    gload_lds16(gB + kb_ + 1024, sb + 16384 + w2k + 1024);                \
  }

  i32x16 acc[4][2] = {};

  STAGE(0); STAGE(1); STAGE(2);           // 12 loads in flight

  #pragma unroll 4
  for (int t = 0; t < Kdim / 64; ++t) {   // 32 K-tiles
    // tile t landed iff outstanding <= 8 (tiles t+1, t+2 = 8 newer loads)
    asm volatile("s_waitcnt vmcnt(8)" ::: "memory");
    __builtin_amdgcn_s_barrier();
    asm volatile("" ::: "memory");        // no LDS reads hoist above barrier

    if (t + 3 < Kdim / 64) STAGE(t + 3);  // into buf[(t-1)&3], freed by barrier

    const char* base = &lds[t & 3][0];
    i32x4 aF[4][2], bF[2][2];
    #pragma unroll
    for (int mi = 0; mi < 4; ++mi)
      #pragma unroll
      for (int ks = 0; ks < 2; ++ks)
        aF[mi][ks] = *(const i32x4*)(base + ((wr * 4 + mi) * 2 + ks) * 1024 + l16);
    #pragma unroll
    for (int ni = 0; ni < 2; ++ni)
      #pragma unroll
      for (int ks = 0; ks < 2; ++ks)
        bF[ni][ks] = *(const i32x4*)(base + 16384 + ((wc * 2 + ni) * 2 + ks) * 1024 + l16);

    __builtin_amdgcn_s_setprio(1);
    #pragma unroll
    for (int ks = 0; ks < 2; ++ks)        // ks outer: dep-chain distance 8
      #pragma unroll
      for (int mi = 0; mi < 4; ++mi)
        #pragma unroll
        for (int ni = 0; ni < 2; ++ni)
          acc[mi][ni] = __builtin_amdgcn_mfma_i32_32x32x32_i8(
              aF[mi][ks], bF[ni][ks], acc[mi][ni], 0, 0, 0);
    __builtin_amdgcn_s_setprio(0);
  }
#undef STAGE

  // epilogue: C/D mapping col = lane&31, row = (r&3) + 8*(r>>2) + 4*(lane>>5)
  const float wsc = scal[0];
  const int   lhi = (l >> 5) * 4, lcol = l & 31;
  float bc[2];
  #pragma unroll
  for (int ni = 0; ni < 2; ++ni)
    bc[ni] = bias[bn * 256 + wc * 64 + ni * 32 + lcol];

  #pragma unroll
  for (int mi = 0; mi < 4; ++mi) {
    const int rb = bm * 256 + wr * 128 + mi * 32 + lhi;
    #pragma unroll
    for (int r = 0; r < 16; ++r) {
      const int   row = rb + (r & 3) + 8 * (r >> 2);
      const float sv  = wsc * xs[row];
      #pragma unroll
      for (int ni = 0; ni < 2; ++ni) {
        const int col = bn * 256 + wc * 64 + ni * 32 + lcol;
        out[(size_t)row * Ndim + col] = (float)acc[mi][ni][r] * sv + bc[ni];
      }
    }
  }
}

// ---------------- launch -----------------------------------------------------
extern "C" void kernel_launch(void* const* d_in, const int* in_sizes, int n_in,
                              void* d_out, int out_size, void* d_ws, size_t ws_size,
                              hipStream_t stream) {
  const float* x    = (const float*)d_in[0];
  const float* wgt  = (const float*)d_in[1];
  const float* bias = (const float*)d_in[2];
  float* out = (float*)d_out;

  float* ws_f = (float*)d_ws;
  float* scal = ws_f;               // 1 float
  float* part = ws_f + 64;          // 256 floats
  float* xs   = ws_f + 1024;        // 16384 floats
  char*  wq   = (char*)(ws_f + 20480);          // 4 MiB packed, 16B-aligned
  char*  xq   = wq + (size_t)WELEMS;            // 32 MiB packed, 16B-aligned

  hipLaunchKernelGGL(k_abs_part,  dim3(256),      dim3(256), 0, stream, wgt, part);
  hipLaunchKernelGGL(k_abs_final, dim3(1),        dim3(256), 0, stream, part, scal);
  hipLaunchKernelGGL(k_wquant,    dim3(64),       dim3(256), 0, stream, wgt, wq, scal);
  hipLaunchKernelGGL(k_xquant,    dim3(Mdim/32),  dim3(256), 0, stream, x, xq, xs);
  hipLaunchKernelGGL(k_gemm,      dim3((Mdim/256)*(Ndim/256)), dim3(512), 0, stream,
                     xq, wq, xs, scal, bias, out);
}

// Round 7
// 149.526 us; speedup vs baseline: 1.0337x; 1.0337x over previous
//
#include <hip/hip_runtime.h>
#include <stdint.h>

typedef int i32x4  __attribute__((ext_vector_type(4)));
typedef int i32x16 __attribute__((ext_vector_type(16)));

static constexpr int Mdim   = 16384;     // B*S = 8*2048
static constexpr int Kdim   = 2048;      // D_IN
static constexpr int Ndim   = 2048;      // D_OUT
static constexpr int WELEMS = Ndim * Kdim;   // 4194304

// Fragment-major pack layout (shared by packers and GEMM):
//   chunk(R, c) = 1024 B at base + (R*64 + c)*1024
//   byte l*16 + b of a chunk holds row R*32 + (l&31), k = c*32 + (l>>5)*16 + b
// so the GEMM's global_load_lds (dest = base + lane*16) reads contiguous 1 KiB.

// ---------------- async global->LDS (16B per lane, lane-ordered dest) -------
__device__ __forceinline__ void gload_lds16(const void* g, void* l) {
  __builtin_amdgcn_global_load_lds(
      (const __attribute__((address_space(1))) void*)g,
      (__attribute__((address_space(3))) void*)l,
      16, 0, 0);
}

// ---------------- K1: partial sums of |w| -----------------------------------
__global__ void k_abs_part(const float* __restrict__ w, float* __restrict__ part) {
  const float4* w4 = (const float4*)w;
  float s = 0.f;
  int idx = blockIdx.x * 256 + threadIdx.x;
  #pragma unroll 4
  for (int i = idx; i < WELEMS / 4; i += 256 * 256) {
    float4 v = w4[i];
    s += fabsf(v.x) + fabsf(v.y) + fabsf(v.z) + fabsf(v.w);
  }
  #pragma unroll
  for (int off = 32; off > 0; off >>= 1) s += __shfl_down(s, off);
  __shared__ float sm[4];
  if ((threadIdx.x & 63) == 0) sm[threadIdx.x >> 6] = s;
  __syncthreads();
  if (threadIdx.x == 0) part[blockIdx.x] = sm[0] + sm[1] + sm[2] + sm[3];
}

// ---------------- K2: finalize scale = mean(|w|) ----------------------------
__global__ void k_abs_final(const float* __restrict__ part, float* __restrict__ scal) {
  float s = part[threadIdx.x];           // exactly 256 partials, block = 256
  #pragma unroll
  for (int off = 32; off > 0; off >>= 1) s += __shfl_down(s, off);
  __shared__ float sm[4];
  if ((threadIdx.x & 63) == 0) sm[threadIdx.x >> 6] = s;
  __syncthreads();
  if (threadIdx.x == 0) scal[0] = (sm[0] + sm[1] + sm[2] + sm[3]) / (float)WELEMS;
}

__device__ __forceinline__ int quant4(float4 v, float sc) {
  int a = (int)rintf(v.x / sc); a = a < -128 ? -128 : (a > 127 ? 127 : a);
  int b = (int)rintf(v.y / sc); b = b < -128 ? -128 : (b > 127 ? 127 : b);
  int c = (int)rintf(v.z / sc); c = c < -128 ? -128 : (c > 127 ? 127 : c);
  int d = (int)rintf(v.w / sc); d = d < -128 ? -128 : (d > 127 ? 127 : d);
  return (a & 255) | ((b & 255) << 8) | ((c & 255) << 16) | ((d & 255) << 24);
}

__device__ __forceinline__ int tern4(float4 v, float s) {
  int a = (int)rintf(v.x / s); a = a < -1 ? -1 : (a > 1 ? 1 : a);
  int b = (int)rintf(v.y / s); b = b < -1 ? -1 : (b > 1 ? 1 : b);
  int c = (int)rintf(v.z / s); c = c < -1 ? -1 : (c > 1 ? 1 : c);
  int d = (int)rintf(v.w / s); d = d < -1 ? -1 : (d > 1 ? 1 : d);
  return (a & 255) | ((b & 255) << 8) | ((c & 255) << 16) | ((d & 255) << 24);
}

// LDS row stride for the transpose buffers: 2052 B (513 dwords, odd ->
// bank = (l*513 + k)%32 spreads 32 rows over all 32 banks; <=2-way = free).
static constexpr int LSTR = 2052;

// ---------------- K3: ternary weight quantize + fragment-major pack ---------
// grid 64 blocks x 512 thr (8 waves); block = 32 rows of w.
__global__ __launch_bounds__(512) void k_wquant(const float* __restrict__ w,
                                                char* __restrict__ wq,
                                                const float* __restrict__ scal) {
  __shared__ char sq[32 * LSTR];
  const float s  = scal[0] + 1e-8f;
  const int   Rg = blockIdx.x;
  const int   wv = threadIdx.x >> 6;     // 0..7
  const int   l  = threadIdx.x & 63;

  #pragma unroll
  for (int it = 0; it < 4; ++it) {
    const int rs = it * 8 + wv;          // row slot 0..31
    const float4* wr = (const float4*)(w + (size_t)(Rg * 32 + rs) * Kdim);
    #pragma unroll
    for (int c = 0; c < 8; ++c)
      *(int*)(&sq[rs * LSTR + (c * 64 + l) * 4]) = tern4(wr[c * 64 + l], s);
  }
  __syncthreads();
  char* dst = wq + (size_t)Rg * 65536;
  #pragma unroll
  for (int i = 0; i < 8; ++i) {
    const int c = i * 8 + wv;            // chunk 0..63
    int p[4];
    #pragma unroll
    for (int j = 0; j < 4; ++j)
      p[j] = *(const int*)(&sq[(l & 31) * LSTR + c * 32 + (l >> 5) * 16 + j * 4]);
    *(int4*)(dst + c * 1024 + l * 16) = make_int4(p[0], p[1], p[2], p[3]);
  }
}

// ---------------- K4: per-row absmax + int8 quantize + pack -----------------
// grid 512 blocks x 512 thr (8 waves); block = 32 rows of x. One row per
// wave-iter -> absmax is a pure shfl reduce; all global traffic coalesced.
__global__ __launch_bounds__(512) void k_xquant(const float* __restrict__ x,
                                                char* __restrict__ xq,
                                                float* __restrict__ xs) {
  __shared__ char sq[32 * LSTR];
  const int Rg = blockIdx.x;
  const int wv = threadIdx.x >> 6;       // 0..7
  const int l  = threadIdx.x & 63;

  #pragma unroll
  for (int it = 0; it < 4; ++it) {
    const int rs  = it * 8 + wv;
    const int row = Rg * 32 + rs;
    const float4* xr = (const float4*)(x + (size_t)row * Kdim);
    float4 v[8];
    float  m = 0.f;
    #pragma unroll
    for (int c = 0; c < 8; ++c) {
      v[c] = xr[c * 64 + l];
      m = fmaxf(m, fmaxf(fmaxf(fabsf(v[c].x), fabsf(v[c].y)),
                         fmaxf(fabsf(v[c].z), fabsf(v[c].w))));
    }
    #pragma unroll
    for (int off = 1; off < 64; off <<= 1) m = fmaxf(m, __shfl_xor(m, off));
    m = fmaxf(m, 1e-8f);
    const float sc = m / 127.0f;
    if (l == 0) xs[row] = sc;
    #pragma unroll
    for (int c = 0; c < 8; ++c)
      *(int*)(&sq[rs * LSTR + (c * 64 + l) * 4]) = quant4(v[c], sc);
  }
  __syncthreads();
  char* dst = xq + (size_t)Rg * 65536;
  #pragma unroll
  for (int i = 0; i < 8; ++i) {
    const int c = i * 8 + wv;
    int p[4];
    #pragma unroll
    for (int j = 0; j < 4; ++j)
      p[j] = *(const int*)(&sq[(l & 31) * LSTR + c * 32 + (l >> 5) * 16 + j * 4]);
    *(int4*)(dst + c * 1024 + l * 16) = make_int4(p[0], p[1], p[2], p[3]);
  }
}

// ---------------- K5: int8 MFMA GEMM, 256x256 tile, BK=64, 2-buf ring -------
// out = (scale*xs[m]) * (xq . wq^T) + bias
// 8 waves (2M x 4N), wave tile 128x64 = acc[4][2] of 32x32 mfma.
// Ring-2 (64 KB LDS -> 2 blocks/CU, cross-block overlap):
//   iter t: vmcnt(4)+raw barrier (t landed, t+1 in flight) -> ds_read frags
//   -> __syncthreads (frees buf t&1; t+1 loads already landed by now)
//   -> STAGE(t+2) -> 16-MFMA setprio cluster.
__global__ __launch_bounds__(512, 2) void k_gemm(
    const char* __restrict__ xq, const char* __restrict__ wq,
    const float* __restrict__ xs, const float* __restrict__ scal,
    const float* __restrict__ bias, float* __restrict__ out) {
  __shared__ __attribute__((aligned(128))) char lds[2][32768];

  // XCD-aware bijective swizzle: 512 blocks, 512 % 8 == 0.
  const int hw  = blockIdx.x;
  const int lin = (hw & 7) * 64 + (hw >> 3);
  const int bm  = lin >> 3;               // 64 M-tiles
  const int bn  = lin & 7;                // 8 N-tiles

  const int tid = threadIdx.x;
  const int w   = tid >> 6;               // wave 0..7
  const int l   = tid & 63;
  const int wr  = w >> 2, wc = w & 3;     // 2 x 4 wave grid
  const int l16 = l * 16;

  // packed sources: wave w stages R-group (bm*8 + w) of A, (bn*8 + w) of B
  const char* gA = xq + (size_t)(bm * 8 + w) * 65536 + l16;
  const char* gB = wq + (size_t)(bn * 8 + w) * 65536 + l16;
  const int   w2k = w * 2048;

#define STAGE(t_)                                                         \
  {                                                                       \
    char* sb = &lds[(t_) & 1][0];                                         \
    const int kb_ = (t_) * 2048;                                          \
    gload_lds16(gA + kb_,        sb + w2k);                               \
    gload_lds16(gA + kb_ + 1024, sb + w2k + 1024);                        \
    gload_lds16(gB + kb_,        sb + 16384 + w2k);                       \
    gload_lds16(gB + kb_ + 1024, sb + 16384 + w2k + 1024);                \
  }

  i32x16 acc[4][2] = {};

  STAGE(0); STAGE(1);                     // 8 loads in flight

  #pragma unroll 2
  for (int t = 0; t < Kdim / 64; ++t) {   // 32 K-tiles
    // tile t landed iff outstanding <= 4 (tile t+1 = 4 newer loads)
    asm volatile("s_waitcnt vmcnt(4)" ::: "memory");
    __builtin_amdgcn_s_barrier();
    asm volatile("" ::: "memory");        // no LDS reads hoist above barrier

    const char* base = &lds[t & 1][0];
    i32x4 aF[4][2], bF[2][2];
    #pragma unroll
    for (int mi = 0; mi < 4; ++mi)
      #pragma unroll
      for (int ks = 0; ks < 2; ++ks)
        aF[mi][ks] = *(const i32x4*)(base + ((wr * 4 + mi) * 2 + ks) * 1024 + l16);
    #pragma unroll
    for (int ni = 0; ni < 2; ++ni)
      #pragma unroll
      for (int ks = 0; ks < 2; ++ks)
        bF[ni][ks] = *(const i32x4*)(base + 16384 + ((wc * 2 + ni) * 2 + ks) * 1024 + l16);

    // frags in regs; frees buf[t&1] for overwrite (drains lgkmcnt; its
    // vmcnt(0) only covers t+1's loads, issued a full tile earlier)
    __syncthreads();
    if (t + 2 < Kdim / 64) STAGE(t + 2);

    __builtin_amdgcn_s_setprio(1);
    #pragma unroll
    for (int ks = 0; ks < 2; ++ks)        // ks outer: dep-chain distance 8
      #pragma unroll
      for (int mi = 0; mi < 4; ++mi)
        #pragma unroll
        for (int ni = 0; ni < 2; ++ni)
          acc[mi][ni] = __builtin_amdgcn_mfma_i32_32x32x32_i8(
              aF[mi][ks], bF[ni][ks], acc[mi][ni], 0, 0, 0);
    __builtin_amdgcn_s_setprio(0);
  }
#undef STAGE

  // epilogue: C/D mapping col = lane&31, row = (r&3) + 8*(r>>2) + 4*(lane>>5)
  const float wsc = scal[0];
  const int   lhi = (l >> 5) * 4, lcol = l & 31;
  float bc[2];
  #pragma unroll
  for (int ni = 0; ni < 2; ++ni)
    bc[ni] = bias[bn * 256 + wc * 64 + ni * 32 + lcol];

  #pragma unroll
  for (int mi = 0; mi < 4; ++mi) {
    const int rb = bm * 256 + wr * 128 + mi * 32 + lhi;
    #pragma unroll
    for (int r = 0; r < 16; ++r) {
      const int   row = rb + (r & 3) + 8 * (r >> 2);
      const float sv  = wsc * xs[row];
      #pragma unroll
      for (int ni = 0; ni < 2; ++ni) {
        const int col = bn * 256 + wc * 64 + ni * 32 + lcol;
        out[(size_t)row * Ndim + col] = (float)acc[mi][ni][r] * sv + bc[ni];
      }
    }
  }
}

// ---------------- launch -----------------------------------------------------
extern "C" void kernel_launch(void* const* d_in, const int* in_sizes, int n_in,
                              void* d_out, int out_size, void* d_ws, size_t ws_size,
                              hipStream_t stream) {
  const float* x    = (const float*)d_in[0];
  const float* wgt  = (const float*)d_in[1];
  const float* bias = (const float*)d_in[2];
  float* out = (float*)d_out;

  float* ws_f = (float*)d_ws;
  float* scal = ws_f;               // 1 float
  float* part = ws_f + 64;          // 256 floats
  float* xs   = ws_f + 1024;        // 16384 floats
  char*  wq   = (char*)(ws_f + 20480);          // 4 MiB packed, 16B-aligned
  char*  xq   = wq + (size_t)WELEMS;            // 32 MiB packed, 16B-aligned

  hipLaunchKernelGGL(k_abs_part,  dim3(256),      dim3(256), 0, stream, wgt, part);
  hipLaunchKernelGGL(k_abs_final, dim3(1),        dim3(256), 0, stream, part, scal);
  hipLaunchKernelGGL(k_wquant,    dim3(64),       dim3(512), 0, stream, wgt, wq, scal);
  hipLaunchKernelGGL(k_xquant,    dim3(Mdim/32),  dim3(512), 0, stream, x, xq, xs);
  hipLaunchKernelGGL(k_gemm,      dim3((Mdim/256)*(Ndim/256)), dim3(512), 0, stream,
                     xq, wq, xs, scal, bias, out);
}

// Round 9
// 134.975 us; speedup vs baseline: 1.1451x; 1.1078x over previous
//
#include <hip/hip_runtime.h>
#include <stdint.h>

typedef int i32x4  __attribute__((ext_vector_type(4)));
typedef int i32x16 __attribute__((ext_vector_type(16)));

static constexpr int Mdim   = 16384;     // B*S = 8*2048
static constexpr int Kdim   = 2048;      // D_IN
static constexpr int Ndim   = 2048;      // D_OUT
static constexpr int WELEMS = Ndim * Kdim;   // 4194304

// Fragment-major pack layout (shared by packers and GEMM):
//   chunk(R, c) = 1024 B at base + (R*64 + c)*1024
//   byte l*16 + b of a chunk holds row R*32 + (l&31), k = c*32 + (l>>5)*16 + b
// so the GEMM's global_load_lds (dest = base + lane*16) reads contiguous 1 KiB.

// ---------------- async global->LDS (16B per lane, lane-ordered dest) -------
__device__ __forceinline__ void gload_lds16(const void* g, void* l) {
  __builtin_amdgcn_global_load_lds(
      (const __attribute__((address_space(1))) void*)g,
      (__attribute__((address_space(3))) void*)l,
      16, 0, 0);
}

// ---------------- K1: partial sums of |w| -----------------------------------
__global__ void k_abs_part(const float* __restrict__ w, float* __restrict__ part) {
  const float4* w4 = (const float4*)w;
  float s = 0.f;
  int idx = blockIdx.x * 256 + threadIdx.x;
  #pragma unroll 4
  for (int i = idx; i < WELEMS / 4; i += 256 * 256) {
    float4 v = w4[i];
    s += fabsf(v.x) + fabsf(v.y) + fabsf(v.z) + fabsf(v.w);
  }
  #pragma unroll
  for (int off = 32; off > 0; off >>= 1) s += __shfl_down(s, off);
  __shared__ float sm[4];
  if ((threadIdx.x & 63) == 0) sm[threadIdx.x >> 6] = s;
  __syncthreads();
  if (threadIdx.x == 0) part[blockIdx.x] = sm[0] + sm[1] + sm[2] + sm[3];
}

// ---------------- K2: finalize scale = mean(|w|) ----------------------------
__global__ void k_abs_final(const float* __restrict__ part, float* __restrict__ scal) {
  float s = part[threadIdx.x];           // exactly 256 partials, block = 256
  #pragma unroll
  for (int off = 32; off > 0; off >>= 1) s += __shfl_down(s, off);
  __shared__ float sm[4];
  if ((threadIdx.x & 63) == 0) sm[threadIdx.x >> 6] = s;
  __syncthreads();
  if (threadIdx.x == 0) scal[0] = (sm[0] + sm[1] + sm[2] + sm[3]) / (float)WELEMS;
}

__device__ __forceinline__ int quant4(float4 v, float sc) {
  int a = (int)rintf(v.x / sc); a = a < -128 ? -128 : (a > 127 ? 127 : a);
  int b = (int)rintf(v.y / sc); b = b < -128 ? -128 : (b > 127 ? 127 : b);
  int c = (int)rintf(v.z / sc); c = c < -128 ? -128 : (c > 127 ? 127 : c);
  int d = (int)rintf(v.w / sc); d = d < -128 ? -128 : (d > 127 ? 127 : d);
  return (a & 255) | ((b & 255) << 8) | ((c & 255) << 16) | ((d & 255) << 24);
}

__device__ __forceinline__ int tern4(float4 v, float s) {
  int a = (int)rintf(v.x / s); a = a < -1 ? -1 : (a > 1 ? 1 : a);
  int b = (int)rintf(v.y / s); b = b < -1 ? -1 : (b > 1 ? 1 : b);
  int c = (int)rintf(v.z / s); c = c < -1 ? -1 : (c > 1 ? 1 : c);
  int d = (int)rintf(v.w / s); d = d < -1 ? -1 : (d > 1 ? 1 : d);
  return (a & 255) | ((b & 255) << 8) | ((c & 255) << 16) | ((d & 255) << 24);
}

// LDS row stride for the transpose buffers: 2052 B (513 dwords, odd ->
// bank = (l*513 + k)%32 spreads 32 rows over all 32 banks; <=2-way = free).
static constexpr int LSTR = 2052;

// ---------------- K3: ternary weight quantize + fragment-major pack ---------
// grid 64 blocks x 512 thr (8 waves); block = 32 rows of w.
__global__ __launch_bounds__(512) void k_wquant(const float* __restrict__ w,
                                                char* __restrict__ wq,
                                                const float* __restrict__ scal) {
  __shared__ char sq[32 * LSTR];
  const float s  = scal[0] + 1e-8f;
  const int   Rg = blockIdx.x;
  const int   wv = threadIdx.x >> 6;     // 0..7
  const int   l  = threadIdx.x & 63;

  #pragma unroll
  for (int it = 0; it < 4; ++it) {
    const int rs = it * 8 + wv;          // row slot 0..31
    const float4* wr = (const float4*)(w + (size_t)(Rg * 32 + rs) * Kdim);
    #pragma unroll
    for (int c = 0; c < 8; ++c)
      *(int*)(&sq[rs * LSTR + (c * 64 + l) * 4]) = tern4(wr[c * 64 + l], s);
  }
  __syncthreads();
  char* dst = wq + (size_t)Rg * 65536;
  #pragma unroll
  for (int i = 0; i < 8; ++i) {
    const int c = i * 8 + wv;            // chunk 0..63
    int p[4];
    #pragma unroll
    for (int j = 0; j < 4; ++j)
      p[j] = *(const int*)(&sq[(l & 31) * LSTR + c * 32 + (l >> 5) * 16 + j * 4]);
    *(int4*)(dst + c * 1024 + l * 16) = make_int4(p[0], p[1], p[2], p[3]);
  }
}

// ---------------- K4: per-row absmax + int8 quantize + pack -----------------
// grid 512 blocks x 512 thr (8 waves); block = 32 rows of x. One row per
// wave-iter -> absmax is a pure shfl reduce; all global traffic coalesced.
__global__ __launch_bounds__(512) void k_xquant(const float* __restrict__ x,
                                                char* __restrict__ xq,
                                                float* __restrict__ xs) {
  __shared__ char sq[32 * LSTR];
  const int Rg = blockIdx.x;
  const int wv = threadIdx.x >> 6;       // 0..7
  const int l  = threadIdx.x & 63;

  #pragma unroll
  for (int it = 0; it < 4; ++it) {
    const int rs  = it * 8 + wv;
    const int row = Rg * 32 + rs;
    const float4* xr = (const float4*)(x + (size_t)row * Kdim);
    float4 v[8];
    float  m = 0.f;
    #pragma unroll
    for (int c = 0; c < 8; ++c) {
      v[c] = xr[c * 64 + l];
      m = fmaxf(m, fmaxf(fmaxf(fabsf(v[c].x), fabsf(v[c].y)),
                         fmaxf(fabsf(v[c].z), fabsf(v[c].w))));
    }
    #pragma unroll
    for (int off = 1; off < 64; off <<= 1) m = fmaxf(m, __shfl_xor(m, off));
    m = fmaxf(m, 1e-8f);
    const float sc = m / 127.0f;
    if (l == 0) xs[row] = sc;
    #pragma unroll
    for (int c = 0; c < 8; ++c)
      *(int*)(&sq[rs * LSTR + (c * 64 + l) * 4]) = quant4(v[c], sc);
  }
  __syncthreads();
  char* dst = xq + (size_t)Rg * 65536;
  #pragma unroll
  for (int i = 0; i < 8; ++i) {
    const int c = i * 8 + wv;
    int p[4];
    #pragma unroll
    for (int j = 0; j < 4; ++j)
      p[j] = *(const int*)(&sq[(l & 31) * LSTR + c * 32 + (l >> 5) * 16 + j * 4]);
    *(int4*)(dst + c * 1024 + l * 16) = make_int4(p[0], p[1], p[2], p[3]);
  }
}

// ---------------- K5: int8 MFMA GEMM, 256x256 tile, BK=64, ring-4 -----------
// out = (scale*xs[m]) * (xq . wq^T) + bias
// 8 waves (2M x 4N), wave tile 128x64 = acc[4][2] of 32x32 mfma.
// Phase-pipelined: fragments are ds_read ONE PHASE AHEAD of the MFMA cluster
// that consumes them, so the LDS pipe runs under the MFMA pipe.
//   BODY(t): [read a1 = tile-t half1 || MFMA half0 (a0,bC in regs)]
//            vmcnt(4) + s_barrier + STAGE(t+3)
//            [read a0,bN = tile-(t+1) half0+B || MFMA half1 (a1,bC)]
// Counted vmcnt never drains to 0 until the tail (t>=30, queue empty).
__global__ __launch_bounds__(512, 2) void k_gemm(
    const char* __restrict__ xq, const char* __restrict__ wq,
    const float* __restrict__ xs, const float* __restrict__ scal,
    const float* __restrict__ bias, float* __restrict__ out) {
  __shared__ __attribute__((aligned(128))) char lds[4][32768];

  // XCD-aware bijective swizzle: 512 blocks, 512 % 8 == 0.
  const int hw  = blockIdx.x;
  const int lin = (hw & 7) * 64 + (hw >> 3);
  const int bm  = lin >> 3;               // 64 M-tiles
  const int bn  = lin & 7;                // 8 N-tiles

  const int tid = threadIdx.x;
  const int w   = tid >> 6;               // wave 0..7
  const int l   = tid & 63;
  const int wr  = w >> 2, wc = w & 3;     // 2 x 4 wave grid
  const int l16 = l * 16;

  // packed sources: wave w stages R-group (bm*8 + w) of A, (bn*8 + w) of B
  const char* gA = xq + (size_t)(bm * 8 + w) * 65536 + l16;
  const char* gB = wq + (size_t)(bn * 8 + w) * 65536 + l16;
  const int   w2k = w * 2048;

#define STAGE(t_)                                                         \
  {                                                                       \
    char* sb = &lds[(t_) & 3][0];                                         \
    const int kb_ = (t_) * 2048;                                          \
    gload_lds16(gA + kb_,        sb + w2k);                               \
    gload_lds16(gA + kb_ + 1024, sb + w2k + 1024);                        \
    gload_lds16(gB + kb_,        sb + 16384 + w2k);                       \
    gload_lds16(gB + kb_ + 1024, sb + 16384 + w2k + 1024);                \
  }

  i32x16 acc[4][2] = {};
  i32x4  a0[2][2], a1[2][2], bC[2][2], bN[2][2];

  STAGE(0); STAGE(1); STAGE(2);           // 12 loads in flight

  asm volatile("s_waitcnt vmcnt(8)" ::: "memory");   // tile 0 landed
  __builtin_amdgcn_s_barrier();
  asm volatile("" ::: "memory");

  // prologue reads: tile-0 half0 + tile-0 B
  #pragma unroll
  for (int mi = 0; mi < 2; ++mi)
    #pragma unroll
    for (int ks = 0; ks < 2; ++ks)
      a0[mi][ks] = *(const i32x4*)(&lds[0][((wr * 4 + mi) * 2 + ks) * 1024 + l16]);
  #pragma unroll
  for (int ni = 0; ni < 2; ++ni)
    #pragma unroll
    for (int ks = 0; ks < 2; ++ks)
      bC[ni][ks] = *(const i32x4*)(&lds[0][16384 + ((wc * 2 + ni) * 2 + ks) * 1024 + l16]);

#define BODY(T, BCU, BNX, VM, DOSTAGE, DONEXT)                              \
  {                                                                         \
    const char* base_ = &lds[(T) & 3][0];                                   \
    _Pragma("unroll") for (int mi = 0; mi < 2; ++mi)                        \
      _Pragma("unroll") for (int ks = 0; ks < 2; ++ks)                      \
        a1[mi][ks] = *(const i32x4*)(base_ + ((wr*4+mi+2)*2+ks)*1024 + l16);\
    __builtin_amdgcn_s_setprio(1);                                          \
    _Pragma("unroll") for (int ks = 0; ks < 2; ++ks)                        \
      _Pragma("unroll") for (int mi = 0; mi < 2; ++mi)                      \
        _Pragma("unroll") for (int ni = 0; ni < 2; ++ni)                    \
          acc[mi][ni] = __builtin_amdgcn_mfma_i32_32x32x32_i8(              \
              a0[mi][ks], BCU[ni][ks], acc[mi][ni], 0, 0, 0);               \
    __builtin_amdgcn_s_setprio(0);                                          \
    asm volatile("s_waitcnt vmcnt(" #VM ")" ::: "memory");                  \
    __builtin_amdgcn_s_barrier();                                           \
    asm volatile("" ::: "memory");                                          \
    if (DOSTAGE) STAGE((T) + 3);                                            \
    if (DONEXT) {                                                           \
      const char* nb_ = &lds[((T) + 1) & 3][0];                             \
      _Pragma("unroll") for (int mi = 0; mi < 2; ++mi)                      \
        _Pragma("unroll") for (int ks = 0; ks < 2; ++ks)                    \
          a0[mi][ks] = *(const i32x4*)(nb_ + ((wr*4+mi)*2+ks)*1024 + l16);  \
      _Pragma("unroll") for (int ni = 0; ni < 2; ++ni)                      \
        _Pragma("unroll") for (int ks = 0; ks < 2; ++ks)                    \
          BNX[ni][ks] = *(const i32x4*)(nb_ + 16384 + ((wc*2+ni)*2+ks)*1024 + l16);\
    }                                                                       \
    __builtin_amdgcn_s_setprio(1);                                          \
    _Pragma("unroll") for (int ks = 0; ks < 2; ++ks)                        \
      _Pragma("unroll") for (int mi = 0; mi < 2; ++mi)                      \
        _Pragma("unroll") for (int ni = 0; ni < 2; ++ni)                    \
          acc[mi+2][ni] = __builtin_amdgcn_mfma_i32_32x32x32_i8(            \
              a1[mi][ks], BCU[ni][ks], acc[mi+2][ni], 0, 0, 0);             \
    __builtin_amdgcn_s_setprio(0);                                          \
  }

  for (int t = 0; t < 28; t += 2) {       // bodies 0..27 (uniform regime)
    BODY(t,     bC, bN, 4, 1, 1);
    BODY(t + 1, bN, bC, 4, 1, 1);
  }
  BODY(28, bC, bN, 4, 1, 1);              // stages tile 31 (last)
  BODY(29, bN, bC, 4, 0, 1);              // outstanding t30,t31 -> t30 landed
  BODY(30, bC, bN, 0, 0, 1);              // queue empties: need vmcnt(0) for t31
  BODY(31, bN, bC, 0, 0, 0);              // last tile, no next reads
#undef BODY
#undef STAGE

  // epilogue: C/D mapping col = lane&31, row = (r&3) + 8*(r>>2) + 4*(lane>>5)
  const float wsc = scal[0];
  const int   lhi = (l >> 5) * 4, lcol = l & 31;
  float bc[2];
  #pragma unroll
  for (int ni = 0; ni < 2; ++ni)
    bc[ni] = bias[bn * 256 + wc * 64 + ni * 32 + lcol];

  #pragma unroll
  for (int mi = 0; mi < 4; ++mi) {
    const int rb = bm * 256 + wr * 128 + mi * 32 + lhi;
    #pragma unroll
    for (int r = 0; r < 16; ++r) {
      const int   row = rb + (r & 3) + 8 * (r >> 2);
      const float sv  = wsc * xs[row];
      #pragma unroll
      for (int ni = 0; ni < 2; ++ni) {
        const int col = bn * 256 + wc * 64 + ni * 32 + lcol;
        out[(size_t)row * Ndim + col] = (float)acc[mi][ni][r] * sv + bc[ni];
      }
    }
  }
}

// ---------------- launch -----------------------------------------------------
extern "C" void kernel_launch(void* const* d_in, const int* in_sizes, int n_in,
                              void* d_out, int out_size, void* d_ws, size_t ws_size,
                              hipStream_t stream) {
  const float* x    = (const float*)d_in[0];
  const float* wgt  = (const float*)d_in[1];
  const float* bias = (const float*)d_in[2];
  float* out = (float*)d_out;

  float* ws_f = (float*)d_ws;
  float* scal = ws_f;               // 1 float
  float* part = ws_f + 64;          // 256 floats
  float* xs   = ws_f + 1024;        // 16384 floats
  char*  wq   = (char*)(ws_f + 20480);          // 4 MiB packed, 16B-aligned
  char*  xq   = wq + (size_t)WELEMS;            // 32 MiB packed, 16B-aligned

  hipLaunchKernelGGL(k_abs_part,  dim3(256),      dim3(256), 0, stream, wgt, part);
  hipLaunchKernelGGL(k_abs_final, dim3(1),        dim3(256), 0, stream, part, scal);
  hipLaunchKernelGGL(k_wquant,    dim3(64),       dim3(512), 0, stream, wgt, wq, scal);
  hipLaunchKernelGGL(k_xquant,    dim3(Mdim/32),  dim3(512), 0, stream, x, xq, xs);
  hipLaunchKernelGGL(k_gemm,      dim3((Mdim/256)*(Ndim/256)), dim3(512), 0, stream,
                     xq, wq, xs, scal, bias, out);
}